// Round 1
// baseline (407.306 us; speedup 1.0000x reference)
//
#include <hip/hip_runtime.h>

#define LQ 1024
#define HN 8
#define BN 8
#define EN 64
#define NP 32

// ---------------------------------------------------------------------------
// Kernel A: sumV[b,h,d] = sum_s V[b,s,h,d]   (64*64 = 4096 floats into d_ws)
// grid 512 = (b,h) * 8 s-octants; block 256 = 4 s-subchunks * 64 d
// ---------------------------------------------------------------------------
__global__ __launch_bounds__(256) void sumv_kernel(const float* __restrict__ V,
                                                   float* __restrict__ sumV) {
  const int bh  = blockIdx.x >> 3;      // 0..63
  const int oct = blockIdx.x & 7;       // 128 s each
  const int d   = threadIdx.x & 63;
  const int sub = threadIdx.x >> 6;     // 0..3, 32 s each
  const int b = bh >> 3, h = bh & 7;
  const int s0 = oct * 128 + sub * 32;

  const float* Vp = V + (size_t)b * LQ * 512 + (size_t)s0 * 512 + h * 64 + d;
  float p = 0.f;
#pragma unroll 8
  for (int j = 0; j < 32; ++j) p += Vp[j * 512];

  __shared__ float red[4][64];
  red[sub][d] = p;
  __syncthreads();
  if (threadIdx.x < 64) {
    const float t = red[0][d] + red[1][d] + red[2][d] + red[3][d];
    atomicAdd(&sumV[bh * 64 + d], t);
  }
}

// ---------------------------------------------------------------------------
// Kernel B: one wave per 64 consecutive rows of one (b,h). Lane = row.
// Scores are lane-local; K/V rows are read with wave-uniform addresses.
// ---------------------------------------------------------------------------
__global__ __launch_bounds__(256) void attn_kernel(const float* __restrict__ Q,
                                                   const float* __restrict__ K,
                                                   const float* __restrict__ V,
                                                   const int* __restrict__ starts,
                                                   const float* __restrict__ sumV,
                                                   float* __restrict__ out) {
  const int lane = threadIdx.x & 63;
  int wid = (blockIdx.x << 2) | (threadIdx.x >> 6);   // 0..1023
  wid = __builtin_amdgcn_readfirstlane(wid);          // wave-uniform -> SGPR
  const int grp = wid & 15;
  const int h   = (wid >> 4) & 7;
  const int b   = wid >> 7;
  const int l   = (grp << 6) | lane;

  // Per-lane contiguous mask range [lo, hi); uncovered -> lo=INT_MAX, hi=0.
  int lo = 0x7fffffff, hi = 0;
#pragma unroll
  for (int p = 0; p < NP; ++p) {
    const int sp = starts[p];                         // uniform scalar load
    if ((unsigned)(l - sp) < 64u) { lo = min(lo, sp); hi = max(hi, sp + 64); }
  }

  // Wave union bounds.
  int rlo = lo, rhi = hi;
#pragma unroll
  for (int off = 32; off; off >>= 1) {
    rlo = min(rlo, __shfl_xor(rlo, off));
    rhi = max(rhi, __shfl_xor(rhi, off));
  }
  rlo = __builtin_amdgcn_readfirstlane(rlo);
  rhi = __builtin_amdgcn_readfirstlane(rhi);

  const size_t rowoff = ((size_t)(b * LQ + l) * HN + h) * EN;
  const float4* Qp = reinterpret_cast<const float4*>(Q + rowoff);
  float4 q[16], acc[16];
#pragma unroll
  for (int i = 0; i < 16; ++i) { q[i] = Qp[i]; acc[i] = make_float4(0.f, 0.f, 0.f, 0.f); }

  const float Cc = 2.0611536224385579e-9f;  // expf(-20): weight of a zero score
  float z = 1024.f * Cc;

  const float* Kb = K + (size_t)b * LQ * 512 + h * 64;
  const float* Vb = V + (size_t)b * LQ * 512 + h * 64;

  for (int s = rlo; s < rhi; ++s) {
    const float4* Kp = reinterpret_cast<const float4*>(Kb + (size_t)s * 512);
    const float4* Vp = reinterpret_cast<const float4*>(Vb + (size_t)s * 512);
    float d0 = 0.f, d1 = 0.f, d2 = 0.f, d3 = 0.f;
#pragma unroll
    for (int i = 0; i < 16; ++i) {
      const float4 k4 = Kp[i];                        // wave-uniform row of K
      d0 += q[i].x * k4.x; d1 += q[i].y * k4.y;
      d2 += q[i].z * k4.z; d3 += q[i].w * k4.w;
    }
    const float score = (d0 + d1) + (d2 + d3);
    const float e  = __expf(score - 20.f);
    const float wm = (s >= lo && s < hi) ? (e - Cc) : 0.f;
    z += wm;
#pragma unroll
    for (int i = 0; i < 16; ++i) {
      const float4 v4 = Vp[i];                        // wave-uniform row of V
      acc[i].x += wm * v4.x; acc[i].y += wm * v4.y;
      acc[i].z += wm * v4.z; acc[i].w += wm * v4.w;
    }
  }

  const float4* SV = reinterpret_cast<const float4*>(sumV + (((b << 3) | h) << 6));
  const float invz = 1.f / z;
  float4* Op = reinterpret_cast<float4*>(out + rowoff);
#pragma unroll
  for (int i = 0; i < 16; ++i) {
    const float4 sv = SV[i];
    float4 o;
    o.x = (acc[i].x + Cc * sv.x) * invz;
    o.y = (acc[i].y + Cc * sv.y) * invz;
    o.z = (acc[i].z + Cc * sv.z) * invz;
    o.w = (acc[i].w + Cc * sv.w) * invz;
    Op[i] = o;
  }
}

// ---------------------------------------------------------------------------
extern "C" void kernel_launch(void* const* d_in, const int* in_sizes, int n_in,
                              void* d_out, int out_size, void* d_ws, size_t ws_size,
                              hipStream_t stream) {
  const float* Q      = (const float*)d_in[0];
  const float* K      = (const float*)d_in[1];
  const float* V      = (const float*)d_in[2];
  const int*   starts = (const int*)d_in[3];
  float* out  = (float*)d_out;
  float* sumV = (float*)d_ws;

  hipMemsetAsync(sumV, 0, BN * HN * EN * sizeof(float), stream);
  sumv_kernel<<<512, 256, 0, stream>>>(V, sumV);
  attn_kernel<<<256, 256, 0, stream>>>(Q, K, V, starts, sumV, out);
}

// Round 2
// 273.331 us; speedup vs baseline: 1.4902x; 1.4902x over previous
//
#include <hip/hip_runtime.h>

#define LQ 1024
#define HN 8
#define BN 8
#define EN 64
#define NP 32
#define NSEG 4

// ---------------------------------------------------------------------------
// Kernel A: partial sumV. partial[bh][qu][d] = sum_{s in qu-th 256-chunk} V[b,s,h,d]
// grid 256 = (bh, qu); block 256 = 4 sub-waves * 64 d. No atomics, no memset.
// ---------------------------------------------------------------------------
__global__ __launch_bounds__(256) void sumv_kernel(const float* __restrict__ V,
                                                   float* __restrict__ partial) {
  const int bh = blockIdx.x >> 2;       // 0..63
  const int qu = blockIdx.x & 3;        // 256 s each
  const int d   = threadIdx.x & 63;
  const int sub = threadIdx.x >> 6;     // 0..3, 64 s each
  const int b = bh >> 3, h = bh & 7;
  const int s0 = qu * 256 + sub * 64;

  const float* Vp = V + (size_t)b * LQ * 512 + (size_t)s0 * 512 + h * 64 + d;
  float p = 0.f;
#pragma unroll 8
  for (int j = 0; j < 64; ++j) p += Vp[j * 512];

  __shared__ float red[4][64];
  red[sub][d] = p;
  __syncthreads();
  if (threadIdx.x < 64) {
    partial[(bh * 4 + qu) * 64 + d] = red[0][d] + red[1][d] + red[2][d] + red[3][d];
  }
}

// ---------------------------------------------------------------------------
// Kernel B: one BLOCK per 64 consecutive rows of one (b,h). Lane = row.
// The wave-union s-range is split across the block's 4 waves (NSEG segments);
// partial (acc, z) tree-reduced through LDS. Scores stay lane-local.
// ---------------------------------------------------------------------------
__global__ __launch_bounds__(256) void attn_kernel(const float* __restrict__ Q,
                                                   const float* __restrict__ K,
                                                   const float* __restrict__ V,
                                                   const int* __restrict__ starts,
                                                   const float* __restrict__ partial,
                                                   float* __restrict__ out) {
  const int lane = threadIdx.x & 63;
  const int w    = threadIdx.x >> 6;            // segment id 0..3
  const int wid  = blockIdx.x;                  // 0..1023 = (b,h,grp)
  const int grp = wid & 15;
  const int h   = (wid >> 4) & 7;
  const int b   = wid >> 7;
  const int l   = (grp << 6) | lane;

  // Per-lane contiguous mask range [lo, hi); uncovered -> lo=INT_MAX, hi=0.
  int lo = 0x7fffffff, hi = 0;
#pragma unroll
  for (int p = 0; p < NP; ++p) {
    const int sp = starts[p];                   // uniform scalar load
    if ((unsigned)(l - sp) < 64u) { lo = min(lo, sp); hi = max(hi, sp + 64); }
  }

  // Wave union bounds (identical across the 4 waves: same lane->l mapping).
  int rlo = lo, rhi = hi;
#pragma unroll
  for (int off = 32; off; off >>= 1) {
    rlo = min(rlo, __shfl_xor(rlo, off));
    rhi = max(rhi, __shfl_xor(rhi, off));
  }
  rlo = __builtin_amdgcn_readfirstlane(rlo);
  rhi = __builtin_amdgcn_readfirstlane(rhi);
  int len = rhi - rlo; if (len < 0) len = 0;
  const int s0 = rlo + (len * w) / NSEG;
  const int s1 = rlo + (len * (w + 1)) / NSEG;

  const size_t rowoff = ((size_t)(b * LQ + l) * HN + h) * EN;
  const float4* Qp = reinterpret_cast<const float4*>(Q + rowoff);
  float4 q[16], acc[16];
#pragma unroll
  for (int i = 0; i < 16; ++i) { q[i] = Qp[i]; acc[i] = make_float4(0.f, 0.f, 0.f, 0.f); }

  const float Cc = 2.0611536224385579e-9f;      // expf(-20): weight of a zero score
  float z = 0.f;

  const float* Kb = K + (size_t)b * LQ * 512 + h * 64;
  const float* Vb = V + (size_t)b * LQ * 512 + h * 64;

#pragma unroll 2
  for (int s = s0; s < s1; ++s) {
    const float4* Kp = reinterpret_cast<const float4*>(Kb + (size_t)s * 512);
    const float4* Vp = reinterpret_cast<const float4*>(Vb + (size_t)s * 512);
    float d0 = 0.f, d1 = 0.f, d2 = 0.f, d3 = 0.f;
#pragma unroll
    for (int i = 0; i < 16; ++i) {
      const float4 k4 = Kp[i];                  // wave-uniform row of K
      d0 += q[i].x * k4.x; d1 += q[i].y * k4.y;
      d2 += q[i].z * k4.z; d3 += q[i].w * k4.w;
    }
    const float score = (d0 + d1) + (d2 + d3);
    const float e  = __expf(score - 20.f);
    const float wm = (s >= lo && s < hi) ? (e - Cc) : 0.f;
    z += wm;
#pragma unroll
    for (int i = 0; i < 16; ++i) {
      const float4 v4 = Vp[i];                  // wave-uniform row of V
      acc[i].x += wm * v4.x; acc[i].y += wm * v4.y;
      acc[i].z += wm * v4.z; acc[i].w += wm * v4.w;
    }
  }

  // ---- block reduction: 4 waves -> wave 0 ----
  __shared__ float4 redA[2][16][64];            // [buf][i][lane]: conflict-free
  __shared__ float  redZ[NSEG][64];
  redZ[w][lane] = z;
  if (w >= 2) {
#pragma unroll
    for (int i = 0; i < 16; ++i) redA[w - 2][i][lane] = acc[i];
  }
  __syncthreads();
  if (w < 2) {
#pragma unroll
    for (int i = 0; i < 16; ++i) {
      const float4 t = redA[w][i][lane];
      acc[i].x += t.x; acc[i].y += t.y; acc[i].z += t.z; acc[i].w += t.w;
    }
  }
  if (w == 1) {
#pragma unroll
    for (int i = 0; i < 16; ++i) redA[1][i][lane] = acc[i];
  }
  __syncthreads();
  if (w == 0) {
#pragma unroll
    for (int i = 0; i < 16; ++i) {
      const float4 t = redA[1][i][lane];
      acc[i].x += t.x; acc[i].y += t.y; acc[i].z += t.z; acc[i].w += t.w;
    }
    const float zt = 1024.f * Cc +
        redZ[0][lane] + redZ[1][lane] + redZ[2][lane] + redZ[3][lane];
    const float invz = 1.f / zt;

    const float4* P0 = reinterpret_cast<const float4*>(partial + (((b << 3) | h) << 8));
    float4* Op = reinterpret_cast<float4*>(out + rowoff);
#pragma unroll
    for (int i = 0; i < 16; ++i) {
      const float4 p0 = P0[i], p1 = P0[16 + i], p2 = P0[32 + i], p3 = P0[48 + i];
      float4 o;
      o.x = (acc[i].x + Cc * (p0.x + p1.x + p2.x + p3.x)) * invz;
      o.y = (acc[i].y + Cc * (p0.y + p1.y + p2.y + p3.y)) * invz;
      o.z = (acc[i].z + Cc * (p0.z + p1.z + p2.z + p3.z)) * invz;
      o.w = (acc[i].w + Cc * (p0.w + p1.w + p2.w + p3.w)) * invz;
      Op[i] = o;
    }
  }
}

// ---------------------------------------------------------------------------
extern "C" void kernel_launch(void* const* d_in, const int* in_sizes, int n_in,
                              void* d_out, int out_size, void* d_ws, size_t ws_size,
                              hipStream_t stream) {
  const float* Q      = (const float*)d_in[0];
  const float* K      = (const float*)d_in[1];
  const float* V      = (const float*)d_in[2];
  const int*   starts = (const int*)d_in[3];
  float* out     = (float*)d_out;
  float* partial = (float*)d_ws;                // 64*4*64 floats

  sumv_kernel<<<256, 256, 0, stream>>>(V, partial);
  attn_kernel<<<1024, 256, 0, stream>>>(Q, K, V, starts, partial, out);
}

// Round 4
// 118.981 us; speedup vs baseline: 3.4233x; 2.2973x over previous
//
#include <hip/hip_runtime.h>

#define LQ 1024
#define HN 8
#define EN 64
#define NP 32
#define NCH 16
#define CC 2.0611536224385579e-9f   // expf(-20)

typedef __attribute__((ext_vector_type(8))) short short8v;
typedef __attribute__((ext_vector_type(4))) float f32x4;

__device__ __forceinline__ unsigned short bf16hi(float f) {
  unsigned u = __float_as_uint(f);
  u += 0x7fffu + ((u >> 16) & 1u);
  return (unsigned short)(u >> 16);
}
__device__ __forceinline__ float bf16tof(unsigned short b) {
  return __uint_as_float(((unsigned)b) << 16);
}

// ---------------------------------------------------------------------------
// sumv: partial[(b*NCH+ch)*512 + d] = sum over 64 s of V[b][s][d]  (d=h*64+e)
// Fully coalesced: 512 threads read one 2 KB row per iteration.
// ---------------------------------------------------------------------------
__global__ __launch_bounds__(512) void sumv_kernel(const float* __restrict__ V,
                                                   float* __restrict__ partial) {
  const int b  = blockIdx.x >> 4;
  const int ch = blockIdx.x & 15;
  const int d  = threadIdx.x;
  const float* Vp = V + (size_t)b * LQ * 512 + (size_t)ch * 64 * 512 + d;
  float p = 0.f;
#pragma unroll 8
  for (int j = 0; j < 64; ++j) p += Vp[(size_t)j * 512];
  partial[(size_t)blockIdx.x * 512 + d] = p;
}

// ---------------------------------------------------------------------------
// attn: one block per (b,h,row-group of 64). Fixed 192-wide s-window, 3 chunks
// of 64. bf16x2 QK^T (3 MFMA terms), bf16 PV (1 term), fp32 accum + exact z.
// ---------------------------------------------------------------------------
__global__ __launch_bounds__(256) void attn_kernel(const float* __restrict__ Q,
                                                   const float* __restrict__ K,
                                                   const float* __restrict__ V,
                                                   const int* __restrict__ starts,
                                                   const float* __restrict__ partial,
                                                   float* __restrict__ out) {
  __shared__ unsigned short Khi[4096], Klo[4096], Vthi[4096], Plds[4096];
  __shared__ int lotab[64], hitab[64];

  const int tid = threadIdx.x;
  const int l  = tid & 63;
  const int w  = tid >> 6;          // wave id: rows w*16..w*16+15 of the group
  const int lr = l & 15;            // row/col selector within a 16-tile
  const int lg = l >> 4;            // k-group
  const int blk = blockIdx.x;
  const int grp = blk & 15, h = (blk >> 4) & 7, b = blk >> 7;
  const int L0 = grp << 6;
  int w0 = grp * 64 - 64;
  w0 = w0 < 0 ? 0 : (w0 > LQ - 192 ? LQ - 192 : w0);

  const float* Qb = Q + (size_t)b * LQ * 512 + h * 64;
  const float* Kb = K + (size_t)b * LQ * 512 + h * 64;
  const float* Vb = V + (size_t)b * LQ * 512 + h * 64;

  // per-row contiguous mask bounds
  if (tid < 64) {
    int row = L0 + tid, lo = 0x7fffffff, hi = 0;
#pragma unroll
    for (int p = 0; p < NP; ++p) {
      int sp = starts[p];
      if ((unsigned)(row - sp) < 64u) { lo = min(lo, sp); hi = max(hi, sp + 64); }
    }
    lotab[tid] = lo; hitab[tid] = hi;
  }

  // Q fragments: A[row=lr, k=lg*8+j] per 32-wide K-step; hi+lo split
  const float* Qrow = Qb + (size_t)(L0 + w * 16 + lr) * 512;
  short8v qhi[2], qlo[2];
#pragma unroll
  for (int ks = 0; ks < 2; ++ks) {
    float4 a = *(const float4*)(Qrow + ks * 32 + lg * 8);
    float4 c = *(const float4*)(Qrow + ks * 32 + lg * 8 + 4);
    short8v hi8, lo8;
#define CVT8(i, fv) { unsigned short hb_ = bf16hi(fv); hi8[i] = (short)hb_; \
                      lo8[i] = (short)bf16hi((fv) - bf16tof(hb_)); }
    CVT8(0, a.x) CVT8(1, a.y) CVT8(2, a.z) CVT8(3, a.w)
    CVT8(4, c.x) CVT8(5, c.y) CVT8(6, c.z) CVT8(7, c.w)
    qhi[ks] = hi8; qlo[ks] = lo8;
  }

  // coalesced stage of one 64-s chunk: K -> Khi/Klo planes, V -> transposed Vthi
  auto stage = [&](int cs) {
#pragma unroll
    for (int t = 0; t < 4; ++t) {
      const int f  = t * 256 + tid;       // 0..1023 float4 slots
      const int sr = f >> 4, c4 = f & 15;
      const float4 kv = *(const float4*)(Kb + (size_t)(cs + sr) * 512 + c4 * 4);
      ushort4 h4, l4;
#define CVTK(i, fv) { unsigned short hb_ = bf16hi(fv); \
                      ((unsigned short*)&h4)[i] = hb_; \
                      ((unsigned short*)&l4)[i] = bf16hi((fv) - bf16tof(hb_)); }
      CVTK(0, kv.x) CVTK(1, kv.y) CVTK(2, kv.z) CVTK(3, kv.w)
      const int kidx = sr * 64 + (((c4 >> 1) ^ (sr & 7)) * 8) + (c4 & 1) * 4;
      *(ushort4*)&Khi[kidx] = h4;
      *(ushort4*)&Klo[kidx] = l4;
      const float4 vv = *(const float4*)(Vb + (size_t)(cs + sr) * 512 + c4 * 4);
#define CVTV(i, fv) { const int d_ = c4 * 4 + i; \
      Vthi[d_ * 64 + (((sr >> 3) ^ (d_ & 7)) * 8) + (sr & 7)] = bf16hi(fv); }
      CVTV(0, vv.x) CVTV(1, vv.y) CVTV(2, vv.z) CVTV(3, vv.w)
    }
  };

  f32x4 oacc[4];
  float zloc[4] = {0.f, 0.f, 0.f, 0.f};
#pragma unroll
  for (int n = 0; n < 4; ++n) oacc[n] = (f32x4){0.f, 0.f, 0.f, 0.f};

  stage(w0);
  __syncthreads();

  int lo_r[4], hi_r[4];
#pragma unroll
  for (int r = 0; r < 4; ++r) {
    lo_r[r] = lotab[w * 16 + lg * 4 + r];
    hi_r[r] = hitab[w * 16 + lg * 4 + r];
  }

  for (int c = 0; c < 3; ++c) {
    const int cs = w0 + c * 64;
    f32x4 sacc[4];
#pragma unroll
    for (int n = 0; n < 4; ++n) sacc[n] = (f32x4){0.f, 0.f, 0.f, 0.f};

    // S = Qhi*Khi + Qhi*Klo + Qlo*Khi   (D: row=lg*4+r, col=n*16+lr)
#pragma unroll
    for (int ks = 0; ks < 2; ++ks) {
#pragma unroll
      for (int n = 0; n < 4; ++n) {
        const int srow = n * 16 + lr;
        const int idx = srow * 64 + (((ks * 4 + lg) ^ (srow & 7)) * 8);
        const short8v kbh = *(const short8v*)&Khi[idx];
        const short8v kbl = *(const short8v*)&Klo[idx];
        sacc[n] = __builtin_amdgcn_mfma_f32_16x16x32_bf16(qhi[ks], kbh, sacc[n], 0, 0, 0);
        sacc[n] = __builtin_amdgcn_mfma_f32_16x16x32_bf16(qhi[ks], kbl, sacc[n], 0, 0, 0);
        sacc[n] = __builtin_amdgcn_mfma_f32_16x16x32_bf16(qlo[ks], kbh, sacc[n], 0, 0, 0);
      }
    }

    // P'' = mask ? exp(S-20)-Cc : 0 ; accumulate z with the bf16-rounded value
#pragma unroll
    for (int n = 0; n < 4; ++n) {
#pragma unroll
      for (int r = 0; r < 4; ++r) {
        const int sg = cs + n * 16 + lr;
        float p = 0.f;
        if (sg >= lo_r[r] && sg < hi_r[r]) p = __expf(sacc[n][r] - 20.f) - CC;
        const unsigned short pb = bf16hi(p);
        zloc[r] += bf16tof(pb);
        const int prow = w * 16 + lg * 4 + r;
        const int sl = n * 16 + lr;
        Plds[prow * 64 + (((sl >> 3) ^ (prow & 7)) * 8) + (sl & 7)] = pb;
      }
    }

    // O += P * V   (same-wave P_lds write->read; compiler orders via lgkmcnt)
#pragma unroll
    for (int ks = 0; ks < 2; ++ks) {
      const int prow = w * 16 + lr;
      const short8v pa = *(const short8v*)&Plds[prow * 64 + (((ks * 4 + lg) ^ (prow & 7)) * 8)];
#pragma unroll
      for (int n = 0; n < 4; ++n) {
        const int d = n * 16 + lr;
        const short8v vbf = *(const short8v*)&Vthi[d * 64 + (((ks * 4 + lg) ^ (d & 7)) * 8)];
        oacc[n] = __builtin_amdgcn_mfma_f32_16x16x32_bf16(pa, vbf, oacc[n], 0, 0, 0);
      }
    }

    if (c < 2) {
      __syncthreads();
      stage(cs + 64);
      __syncthreads();
    }
  }

  // z: reduce over the 16 col-lanes (lane bits 0..3)
#pragma unroll
  for (int r = 0; r < 4; ++r) {
#pragma unroll
    for (int off = 1; off < 16; off <<= 1) zloc[r] += __shfl_xor(zloc[r], off, 64);
  }

  // background sumV
  float sv[4];
#pragma unroll
  for (int n = 0; n < 4; ++n) {
    float s = 0.f;
    const float* pp = partial + (size_t)b * NCH * 512 + h * 64 + n * 16 + lr;
#pragma unroll
    for (int ch = 0; ch < NCH; ++ch) s += pp[(size_t)ch * 512];
    sv[n] = s;
  }

  float* Ob = out + ((size_t)b * LQ + L0 + w * 16 + lg * 4) * 512 + h * 64;
#pragma unroll
  for (int r = 0; r < 4; ++r) {
    const float invz = 1.f / (zloc[r] + 1024.f * CC);
#pragma unroll
    for (int n = 0; n < 4; ++n)
      Ob[(size_t)r * 512 + n * 16 + lr] = (oacc[n][r] + CC * sv[n]) * invz;
  }
}

// ---------------------------------------------------------------------------
extern "C" void kernel_launch(void* const* d_in, const int* in_sizes, int n_in,
                              void* d_out, int out_size, void* d_ws, size_t ws_size,
                              hipStream_t stream) {
  const float* Q      = (const float*)d_in[0];
  const float* K      = (const float*)d_in[1];
  const float* V      = (const float*)d_in[2];
  const int*   starts = (const int*)d_in[3];
  float* out     = (float*)d_out;
  float* partial = (float*)d_ws;               // 8*16*512 floats = 256 KB

  sumv_kernel<<<128, 512, 0, stream>>>(V, partial);
  attn_kernel<<<1024, 256, 0, stream>>>(Q, K, V, starts, partial, out);
}

// Round 6
// 114.334 us; speedup vs baseline: 3.5624x; 1.0406x over previous
//
#include <hip/hip_runtime.h>

#define LQ 1024
#define NP 32
#define CC 2.0611536224385579e-9f   // expf(-20)

typedef __attribute__((ext_vector_type(8))) short short8v;
typedef __attribute__((ext_vector_type(4))) float f32x4;

__device__ __forceinline__ unsigned short bf16hi(float f) {
  unsigned u = __float_as_uint(f);
  u += 0x7fffu + ((u >> 16) & 1u);
  return (unsigned short)(u >> 16);
}
__device__ __forceinline__ float bf16tof(unsigned short b) {
  return __uint_as_float(((unsigned)b) << 16);
}
__device__ __forceinline__ void gload16(const unsigned short* g, unsigned short* l) {
  __builtin_amdgcn_global_load_lds(
      (const __attribute__((address_space(1))) unsigned int*)g,
      (__attribute__((address_space(3))) unsigned int*)l, 16, 0, 0);
}
#define SWZD(d) (((d) & 7) ^ ((d) >> 3))

// ---------------------------------------------------------------------------
// prep: block = (b,h,sc). Emits planes[(bh*16+sc)*12288] = [Khi 4K|Klo 4K|Vt 4K]
// shorts in attn-LDS image order, plus partial[blk*64+d] = sum_s V (fp32).
// ---------------------------------------------------------------------------
__global__ __launch_bounds__(256) void prep_kernel(const float* __restrict__ K,
                                                   const float* __restrict__ V,
                                                   unsigned short* __restrict__ planes,
                                                   float* __restrict__ partial) {
  __shared__ unsigned short Vt[4096];
  __shared__ float red[16][64];
  const int blk = blockIdx.x;
  const int sc = blk & 15, h = (blk >> 4) & 7, b = blk >> 7;
  const int tid = threadIdx.x;
  unsigned short* pb = planes + (size_t)blk * 12288;
  const float* Kb = K + ((size_t)b * LQ + sc * 64) * 512 + h * 64;
  const float* Vb = V + ((size_t)b * LQ + sc * 64) * 512 + h * 64;
  const int c4 = tid & 15;
  float facc[4] = {0.f, 0.f, 0.f, 0.f};
#pragma unroll
  for (int t = 0; t < 4; ++t) {
    const int sr = t * 16 + (tid >> 4);
    const float4 kv = *(const float4*)(Kb + (size_t)sr * 512 + c4 * 4);
    ushort4 h4, l4;
    {
      float fv[4] = {kv.x, kv.y, kv.z, kv.w};
#pragma unroll
      for (int i = 0; i < 4; ++i) {
        unsigned short hb = bf16hi(fv[i]);
        ((unsigned short*)&h4)[i] = hb;
        ((unsigned short*)&l4)[i] = bf16hi(fv[i] - bf16tof(hb));
      }
    }
    const int kidx = sr * 64 + (((c4 >> 1) ^ (sr & 7)) * 8) + (c4 & 1) * 4;
    *(ushort4*)&pb[kidx] = h4;
    *(ushort4*)&pb[4096 + kidx] = l4;
    const float4 vv = *(const float4*)(Vb + (size_t)sr * 512 + c4 * 4);
    {
      float fv[4] = {vv.x, vv.y, vv.z, vv.w};
#pragma unroll
      for (int i = 0; i < 4; ++i) {
        facc[i] += fv[i];
        const int d = c4 * 4 + i;
        Vt[d * 64 + (((sr >> 3) ^ SWZD(d)) * 8) + (sr & 7)] = bf16hi(fv[i]);
      }
    }
  }
#pragma unroll
  for (int i = 0; i < 4; ++i) red[tid >> 4][c4 * 4 + i] = facc[i];
  __syncthreads();
  if (tid < 64) {
    float s = 0.f;
#pragma unroll
    for (int g = 0; g < 16; ++g) s += red[g][tid];
    partial[(size_t)blk * 64 + tid] = s;
  }
  // copy transposed V plane out: 512 x 16 B covers all 4096 shorts
#pragma unroll
  for (int it = 0; it < 2; ++it) {
    const int idx = (it * 256 + tid) * 8;
    *(uint4*)&pb[8192 + idx] = *(const uint4*)&Vt[idx];
  }
}

// ---------------------------------------------------------------------------
// attn: block per (b,h,row-group). Stages pre-converted planes via
// global_load_lds (double-buffered), skips dead chunks, bf16x2 QK^T + bf16 PV.
// ---------------------------------------------------------------------------
__global__ __launch_bounds__(256) void attn_kernel(const float* __restrict__ Q,
                                                   const unsigned short* __restrict__ planes,
                                                   const int* __restrict__ starts,
                                                   const float* __restrict__ partial,
                                                   float* __restrict__ out) {
  __shared__ unsigned short ldsb[2][12288];
  __shared__ unsigned short Plds[4096];
  __shared__ int lotab[64], hitab[64];

  const int tid = threadIdx.x;
  const int lane = tid & 63;
  const int w = tid >> 6;
  const int lr = lane & 15, lg = lane >> 4;
  const int blk = ((blockIdx.x & 7) << 7) | (blockIdx.x >> 3);  // XCD swizzle
  const int grp = blk & 15, bh = blk >> 4;
  const int h = bh & 7, b = bh >> 3;
  const int L0 = grp << 6;
  int w0 = L0 - 64; w0 = w0 < 0 ? 0 : (w0 > LQ - 192 ? LQ - 192 : w0);

  if (tid < 64) {
    int row = L0 + tid, lo = 0x7fffffff, hi = 0;
#pragma unroll
    for (int p = 0; p < NP; ++p) {
      int sp = starts[p];
      if ((unsigned)(row - sp) < 64u) { lo = min(lo, sp); hi = max(hi, sp + 64); }
    }
    lotab[tid] = lo; hitab[tid] = hi;
  }
  int lo_l = 0x7fffffff, hi_l = 0;
  {
    int row = L0 + lane;
#pragma unroll
    for (int p = 0; p < NP; ++p) {
      int sp = starts[p];
      if ((unsigned)(row - sp) < 64u) { lo_l = min(lo_l, sp); hi_l = max(hi_l, sp + 64); }
    }
  }
  int rlo = lo_l, rhi = hi_l;
#pragma unroll
  for (int off = 32; off; off >>= 1) {
    rlo = min(rlo, __shfl_xor(rlo, off));
    rhi = max(rhi, __shfl_xor(rhi, off));
  }
  rlo = __builtin_amdgcn_readfirstlane(rlo);
  rhi = __builtin_amdgcn_readfirstlane(rhi);

  int csl[3], ncs = 0;
#pragma unroll
  for (int c = 0; c < 3; ++c) {
    const int cs = w0 + c * 64;
    if (cs < rhi && cs + 64 > rlo) csl[ncs++] = cs;
  }

  const unsigned short* gpb = planes + (size_t)bh * 16 * 12288;
  auto stage = [&](int cs, int buf) {
    const unsigned short* gp = gpb + (size_t)(cs >> 6) * 12288 + w * 3072 + lane * 8;
    unsigned short* lp = &ldsb[buf][w * 3072];
#pragma unroll
    for (int k = 0; k < 6; ++k) gload16(gp + k * 512, lp + k * 512);
  };

  if (ncs) stage(csl[0], 0);

  // Q fragments (fp32 -> bf16 hi/lo), row = L0 + w*16 + lr
  const float* Qrow = Q + ((size_t)b * LQ + L0 + w * 16 + lr) * 512 + h * 64;
  short8v qhi[2], qlo[2];
#pragma unroll
  for (int ks = 0; ks < 2; ++ks) {
    float4 a = *(const float4*)(Qrow + ks * 32 + lg * 8);
    float4 c = *(const float4*)(Qrow + ks * 32 + lg * 8 + 4);
    short8v hi8, lo8;
    float fv[8] = {a.x, a.y, a.z, a.w, c.x, c.y, c.z, c.w};
#pragma unroll
    for (int i = 0; i < 8; ++i) {
      unsigned short hb = bf16hi(fv[i]);
      hi8[i] = (short)hb;
      lo8[i] = (short)bf16hi(fv[i] - bf16tof(hb));
    }
    qhi[ks] = hi8; qlo[ks] = lo8;
  }

  __syncthreads();

  int lo_r[4], hi_r[4];
#pragma unroll
  for (int r = 0; r < 4; ++r) {
    lo_r[r] = lotab[w * 16 + lg * 4 + r];
    hi_r[r] = hitab[w * 16 + lg * 4 + r];
  }

  f32x4 oacc[4];
  float zloc[4] = {0.f, 0.f, 0.f, 0.f};
#pragma unroll
  for (int n = 0; n < 4; ++n) oacc[n] = (f32x4){0.f, 0.f, 0.f, 0.f};

  for (int i = 0; i < ncs; ++i) {
    if (i + 1 < ncs) stage(csl[i + 1], (i + 1) & 1);
    const unsigned short* Khi_l = &ldsb[i & 1][0];
    const unsigned short* Klo_l = &ldsb[i & 1][4096];
    const unsigned short* Vt_l  = &ldsb[i & 1][8192];
    const int cs = csl[i];

    f32x4 sacc[4];
#pragma unroll
    for (int n = 0; n < 4; ++n) sacc[n] = (f32x4){0.f, 0.f, 0.f, 0.f};

#pragma unroll
    for (int ks = 0; ks < 2; ++ks) {
#pragma unroll
      for (int n = 0; n < 4; ++n) {
        const int srow = n * 16 + lr;
        const int idx = srow * 64 + (((ks * 4 + lg) ^ (srow & 7)) * 8);
        const short8v kbh = *(const short8v*)&Khi_l[idx];
        const short8v kbl = *(const short8v*)&Klo_l[idx];
        sacc[n] = __builtin_amdgcn_mfma_f32_16x16x32_bf16(qhi[ks], kbh, sacc[n], 0, 0, 0);
        sacc[n] = __builtin_amdgcn_mfma_f32_16x16x32_bf16(qhi[ks], kbl, sacc[n], 0, 0, 0);
        sacc[n] = __builtin_amdgcn_mfma_f32_16x16x32_bf16(qlo[ks], kbh, sacc[n], 0, 0, 0);
      }
    }

#pragma unroll
    for (int n = 0; n < 4; ++n) {
#pragma unroll
      for (int r = 0; r < 4; ++r) {
        const int sg = cs + n * 16 + lr;
        float p = 0.f;
        if (sg >= lo_r[r] && sg < hi_r[r]) p = __expf(sacc[n][r] - 20.f) - CC;
        const unsigned short pb16 = bf16hi(p);
        zloc[r] += bf16tof(pb16);
        const int prow = w * 16 + lg * 4 + r;
        const int sl = n * 16 + lr;
        Plds[prow * 64 + (((sl >> 3) ^ ((prow & 7) ^ (prow >> 3))) * 8) + (sl & 7)] = pb16;
      }
    }

#pragma unroll
    for (int ks = 0; ks < 2; ++ks) {
      const int prow = w * 16 + lr;
      const short8v pa = *(const short8v*)
          &Plds[prow * 64 + (((ks * 4 + lg) ^ ((prow & 7) ^ (prow >> 3))) * 8)];
#pragma unroll
      for (int n = 0; n < 4; ++n) {
        const int d = n * 16 + lr;
        const short8v vb = *(const short8v*)&Vt_l[d * 64 + (((ks * 4 + lg) ^ SWZD(d)) * 8)];
        oacc[n] = __builtin_amdgcn_mfma_f32_16x16x32_bf16(pa, vb, oacc[n], 0, 0, 0);
      }
    }
    __syncthreads();
  }

  // z: reduce over 16 column-lanes
#pragma unroll
  for (int r = 0; r < 4; ++r) {
#pragma unroll
    for (int off = 1; off < 16; off <<= 1) zloc[r] += __shfl_xor(zloc[r], off, 64);
  }

  // background sumV
  float sv[4];
#pragma unroll
  for (int n = 0; n < 4; ++n) {
    float s = 0.f;
#pragma unroll
    for (int sc2 = 0; sc2 < 16; ++sc2)
      s += partial[(size_t)bh * 1024 + sc2 * 64 + n * 16 + lr];
    sv[n] = s;
  }

  float* Ob = out + ((size_t)b * LQ + L0 + w * 16 + lg * 4) * 512 + h * 64;
#pragma unroll
  for (int r = 0; r < 4; ++r) {
    const float invz = 1.f / (zloc[r] + 1024.f * CC);
#pragma unroll
    for (int n = 0; n < 4; ++n)
      Ob[(size_t)r * 512 + n * 16 + lr] = (oacc[n][r] + CC * sv[n]) * invz;
  }
}

// ---------------------------------------------------------------------------
extern "C" void kernel_launch(void* const* d_in, const int* in_sizes, int n_in,
                              void* d_out, int out_size, void* d_ws, size_t ws_size,
                              hipStream_t stream) {
  const float* Q      = (const float*)d_in[0];
  const float* K      = (const float*)d_in[1];
  const float* V      = (const float*)d_in[2];
  const int*   starts = (const int*)d_in[3];
  float* out = (float*)d_out;
  unsigned short* planes = (unsigned short*)d_ws;                     // 25,165,824 B
  float* partial = (float*)((char*)d_ws + 25165824);                  // 64*16*64 fp32

  prep_kernel<<<1024, 256, 0, stream>>>(K, V, planes, partial);
  attn_kernel<<<1024, 256, 0, stream>>>(Q, planes, starts, partial, out);
}

// Round 7
// 113.991 us; speedup vs baseline: 3.5731x; 1.0030x over previous
//
#include <hip/hip_runtime.h>

#define LQ 1024
#define NP 32
#define CC 2.0611536224385579e-9f   // expf(-20)

typedef __attribute__((ext_vector_type(8))) short short8v;
typedef __attribute__((ext_vector_type(4))) float f32x4;

__device__ __forceinline__ unsigned short bf16hi(float f) {
  unsigned u = __float_as_uint(f);
  u += 0x7fffu + ((u >> 16) & 1u);
  return (unsigned short)(u >> 16);
}
__device__ __forceinline__ float bf16tof(unsigned short b) {
  return __uint_as_float(((unsigned)b) << 16);
}
#define SWZD(d) (((d) & 7) ^ ((d) >> 3))

// ---------------------------------------------------------------------------
// sumv: partial[(bh*16+sc)*64 + d] = sum_{s in chunk sc} V[b][s][h*64+d]
// 1024 blocks x 256 threads, 16 KB coalesced read per block.
// ---------------------------------------------------------------------------
__global__ __launch_bounds__(256) void sumv_kernel(const float* __restrict__ V,
                                                   float* __restrict__ partial) {
  __shared__ float red[16][64];
  const int blk = blockIdx.x;
  const int sc = blk & 15, h = (blk >> 4) & 7, b = blk >> 7;
  const int tid = threadIdx.x;
  const int c4 = tid & 15;
  const float* Vb = V + ((size_t)b * LQ + sc * 64) * 512 + h * 64;
  float4 facc = make_float4(0.f, 0.f, 0.f, 0.f);
#pragma unroll
  for (int t = 0; t < 4; ++t) {
    const int sr = t * 16 + (tid >> 4);
    const float4 v = *(const float4*)(Vb + (size_t)sr * 512 + c4 * 4);
    facc.x += v.x; facc.y += v.y; facc.z += v.z; facc.w += v.w;
  }
  *(float4*)&red[tid >> 4][c4 * 4] = facc;
  __syncthreads();
  if (tid < 64) {
    float s = 0.f;
#pragma unroll
    for (int g = 0; g < 16; ++g) s += red[g][tid];
    partial[(size_t)blk * 64 + tid] = s;
  }
}

// ---------------------------------------------------------------------------
// attn: fused. Block per (b,h,row-group). K/V fp32 -> regs (issued one chunk
// ahead) -> convert -> single swizzled LDS buffer -> bf16x2 QK^T + bf16 PV.
// ---------------------------------------------------------------------------
__global__ __launch_bounds__(256) void attn_kernel(const float* __restrict__ Q,
                                                   const float* __restrict__ K,
                                                   const float* __restrict__ V,
                                                   const int* __restrict__ starts,
                                                   const float* __restrict__ partial,
                                                   float* __restrict__ out) {
  __shared__ unsigned short Kh[4096], Kl[4096], Vt[4096], Plds[4096];
  __shared__ int lotab[64], hitab[64];

  const int tid = threadIdx.x;
  const int lane = tid & 63;
  const int w = tid >> 6;
  const int lr = lane & 15, lg = lane >> 4;
  const int blk = ((blockIdx.x & 7) << 7) | (blockIdx.x >> 3);  // XCD swizzle
  const int grp = blk & 15, bh = blk >> 4;
  const int h = bh & 7, b = bh >> 3;
  const int L0 = grp << 6;
  int w0 = L0 - 64; w0 = w0 < 0 ? 0 : (w0 > LQ - 192 ? LQ - 192 : w0);

  const float* Kb = K + (size_t)b * LQ * 512 + h * 64;
  const float* Vb = V + (size_t)b * LQ * 512 + h * 64;

  if (tid < 64) {
    int row = L0 + tid, lo = 0x7fffffff, hi = 0;
#pragma unroll
    for (int p = 0; p < NP; ++p) {
      int sp = starts[p];
      if ((unsigned)(row - sp) < 64u) { lo = min(lo, sp); hi = max(hi, sp + 64); }
    }
    lotab[tid] = lo; hitab[tid] = hi;
  }
  int lo_l = 0x7fffffff, hi_l = 0;
  {
    int row = L0 + lane;
#pragma unroll
    for (int p = 0; p < NP; ++p) {
      int sp = starts[p];
      if ((unsigned)(row - sp) < 64u) { lo_l = min(lo_l, sp); hi_l = max(hi_l, sp + 64); }
    }
  }
  int rlo = lo_l, rhi = hi_l;
#pragma unroll
  for (int off = 32; off; off >>= 1) {
    rlo = min(rlo, __shfl_xor(rlo, off));
    rhi = max(rhi, __shfl_xor(rhi, off));
  }
  rlo = __builtin_amdgcn_readfirstlane(rlo);
  rhi = __builtin_amdgcn_readfirstlane(rhi);

  int csl[3], ncs = 0;
#pragma unroll
  for (int c = 0; c < 3; ++c) {
    const int cs = w0 + c * 64;
    if (cs < rhi && cs + 64 > rlo) csl[ncs++] = cs;
  }

  // staging registers (one chunk ahead)
  float4 kreg[4], vreg[4];
  const int c4 = tid & 15;
  auto gload = [&](int cs) {
#pragma unroll
    for (int t = 0; t < 4; ++t) {
      const int sr = t * 16 + (tid >> 4);
      kreg[t] = *(const float4*)(Kb + (size_t)(cs + sr) * 512 + c4 * 4);
      vreg[t] = *(const float4*)(Vb + (size_t)(cs + sr) * 512 + c4 * 4);
    }
  };
  auto lwrite = [&]() {
#pragma unroll
    for (int t = 0; t < 4; ++t) {
      const int sr = t * 16 + (tid >> 4);
      ushort4 h4, l4;
      float fk[4] = {kreg[t].x, kreg[t].y, kreg[t].z, kreg[t].w};
#pragma unroll
      for (int i = 0; i < 4; ++i) {
        unsigned short hb = bf16hi(fk[i]);
        ((unsigned short*)&h4)[i] = hb;
        ((unsigned short*)&l4)[i] = bf16hi(fk[i] - bf16tof(hb));
      }
      const int kidx = sr * 64 + (((c4 >> 1) ^ (sr & 7)) * 8) + (c4 & 1) * 4;
      *(ushort4*)&Kh[kidx] = h4;
      *(ushort4*)&Kl[kidx] = l4;
      float fv[4] = {vreg[t].x, vreg[t].y, vreg[t].z, vreg[t].w};
#pragma unroll
      for (int i = 0; i < 4; ++i) {
        const int d = c4 * 4 + i;
        Vt[d * 64 + (((sr >> 3) ^ SWZD(d)) * 8) + (sr & 7)] = bf16hi(fv[i]);
      }
    }
  };

  if (ncs) gload(csl[0]);

  // Q fragments (fp32 -> bf16 hi/lo), row = L0 + w*16 + lr
  const float* Qrow = Q + ((size_t)b * LQ + L0 + w * 16 + lr) * 512 + h * 64;
  short8v qhi[2], qlo[2];
#pragma unroll
  for (int ks = 0; ks < 2; ++ks) {
    float4 a = *(const float4*)(Qrow + ks * 32 + lg * 8);
    float4 c = *(const float4*)(Qrow + ks * 32 + lg * 8 + 4);
    short8v hi8, lo8;
    float fv[8] = {a.x, a.y, a.z, a.w, c.x, c.y, c.z, c.w};
#pragma unroll
    for (int i = 0; i < 8; ++i) {
      unsigned short hb = bf16hi(fv[i]);
      hi8[i] = (short)hb;
      lo8[i] = (short)bf16hi(fv[i] - bf16tof(hb));
    }
    qhi[ks] = hi8; qlo[ks] = lo8;
  }

  if (ncs) {
    lwrite();
    if (ncs > 1) gload(csl[1]);
  }
  __syncthreads();

  int lo_r[4], hi_r[4];
#pragma unroll
  for (int r = 0; r < 4; ++r) {
    lo_r[r] = lotab[w * 16 + lg * 4 + r];
    hi_r[r] = hitab[w * 16 + lg * 4 + r];
  }

  f32x4 oacc[4];
  float zloc[4] = {0.f, 0.f, 0.f, 0.f};
#pragma unroll
  for (int n = 0; n < 4; ++n) oacc[n] = (f32x4){0.f, 0.f, 0.f, 0.f};

  for (int i = 0; i < ncs; ++i) {
    const int cs = csl[i];
    f32x4 sacc[4];
#pragma unroll
    for (int n = 0; n < 4; ++n) sacc[n] = (f32x4){0.f, 0.f, 0.f, 0.f};

#pragma unroll
    for (int ks = 0; ks < 2; ++ks) {
#pragma unroll
      for (int n = 0; n < 4; ++n) {
        const int srow = n * 16 + lr;
        const int idx = srow * 64 + (((ks * 4 + lg) ^ (srow & 7)) * 8);
        const short8v kbh = *(const short8v*)&Kh[idx];
        const short8v kbl = *(const short8v*)&Kl[idx];
        sacc[n] = __builtin_amdgcn_mfma_f32_16x16x32_bf16(qhi[ks], kbh, sacc[n], 0, 0, 0);
        sacc[n] = __builtin_amdgcn_mfma_f32_16x16x32_bf16(qhi[ks], kbl, sacc[n], 0, 0, 0);
        sacc[n] = __builtin_amdgcn_mfma_f32_16x16x32_bf16(qlo[ks], kbh, sacc[n], 0, 0, 0);
      }
    }

#pragma unroll
    for (int n = 0; n < 4; ++n) {
#pragma unroll
      for (int r = 0; r < 4; ++r) {
        const int sg = cs + n * 16 + lr;
        float p = 0.f;
        if (sg >= lo_r[r] && sg < hi_r[r]) p = __expf(sacc[n][r] - 20.f) - CC;
        const unsigned short pb16 = bf16hi(p);
        zloc[r] += bf16tof(pb16);
        const int prow = w * 16 + lg * 4 + r;
        const int sl = n * 16 + lr;
        Plds[prow * 64 + (((sl >> 3) ^ ((prow & 7) ^ (prow >> 3))) * 8) + (sl & 7)] = pb16;
      }
    }

#pragma unroll
    for (int ks = 0; ks < 2; ++ks) {
      const int prow = w * 16 + lr;
      const short8v pa = *(const short8v*)
          &Plds[prow * 64 + (((ks * 4 + lg) ^ ((prow & 7) ^ (prow >> 3))) * 8)];
#pragma unroll
      for (int n = 0; n < 4; ++n) {
        const int d = n * 16 + lr;
        const short8v vb = *(const short8v*)&Vt[d * 64 + (((ks * 4 + lg) ^ SWZD(d)) * 8)];
        oacc[n] = __builtin_amdgcn_mfma_f32_16x16x32_bf16(pa, vb, oacc[n], 0, 0, 0);
      }
    }

    if (i + 1 < ncs) {
      __syncthreads();              // all waves done reading current planes
      lwrite();                     // regs (chunk i+1) -> LDS
      if (i + 2 < ncs) gload(csl[i + 2]);   // next-next chunk in flight
      __syncthreads();              // planes ready
    }
  }

  // z: reduce over 16 column-lanes
#pragma unroll
  for (int r = 0; r < 4; ++r) {
#pragma unroll
    for (int off = 1; off < 16; off <<= 1) zloc[r] += __shfl_xor(zloc[r], off, 64);
  }

  // background sumV
  float sv[4];
#pragma unroll
  for (int n = 0; n < 4; ++n) {
    float s = 0.f;
#pragma unroll
    for (int sc2 = 0; sc2 < 16; ++sc2)
      s += partial[(size_t)bh * 1024 + sc2 * 64 + n * 16 + lr];
    sv[n] = s;
  }

  float* Ob = out + ((size_t)b * LQ + L0 + w * 16 + lg * 4) * 512 + h * 64;
#pragma unroll
  for (int r = 0; r < 4; ++r) {
    const float invz = 1.f / (zloc[r] + 1024.f * CC);
#pragma unroll
    for (int n = 0; n < 4; ++n)
      Ob[(size_t)r * 512 + n * 16 + lr] = (oacc[n][r] + CC * sv[n]) * invz;
  }
}

// ---------------------------------------------------------------------------
extern "C" void kernel_launch(void* const* d_in, const int* in_sizes, int n_in,
                              void* d_out, int out_size, void* d_ws, size_t ws_size,
                              hipStream_t stream) {
  const float* Q      = (const float*)d_in[0];
  const float* K      = (const float*)d_in[1];
  const float* V      = (const float*)d_in[2];
  const int*   starts = (const int*)d_in[3];
  float* out     = (float*)d_out;
  float* partial = (float*)d_ws;               // 64*16*64 fp32 = 256 KB

  sumv_kernel<<<1024, 256, 0, stream>>>(V, partial);
  attn_kernel<<<1024, 256, 0, stream>>>(Q, K, V, starts, partial, out);
}